// Round 8
// baseline (312.081 us; speedup 1.0000x reference)
//
#include <hip/hip_runtime.h>
#include <hip/hip_bf16.h>
#include <stdint.h>

typedef __bf16 bf16x8 __attribute__((ext_vector_type(8)));
typedef float f32x4 __attribute__((ext_vector_type(4)));

// ---------------- helpers ----------------

__device__ __forceinline__ void gld_lds16(const void* g, void* l) {
  // global -> LDS direct DMA, 16B per lane (wave-uniform base + lane*16).
  __builtin_amdgcn_global_load_lds(
      (const __attribute__((address_space(1))) unsigned int*)g,
      (__attribute__((address_space(3))) unsigned int*)l, 16, 0, 0);
}

__device__ __forceinline__ uint16_t f2bf(float f) {
  uint32_t u = __float_as_uint(f);
  return (uint16_t)((u + 0x7fffu + ((u >> 16) & 1u)) >> 16);
}

__device__ __forceinline__ uint32_t pk2(float a, float b) {
  return (uint32_t)f2bf(a) | ((uint32_t)f2bf(b) << 16);
}

union BF8U {
  uint32_t u[4];
  bf16x8 v;
};

__device__ __forceinline__ bf16x8 pack8(float4 f0, float4 f1) {
  BF8U r;
  r.u[0] = pk2(f0.x, f0.y);
  r.u[1] = pk2(f0.z, f0.w);
  r.u[2] = pk2(f1.x, f1.y);
  r.u[3] = pk2(f1.z, f1.w);
  return r.v;
}

// ---------------- V[h][t] = sum_k CM[t][h][k] * cla_w[k] ----------------
__global__ __launch_bounds__(256) void cmv_kernel(const float* __restrict__ CM,
                                                  const float* __restrict__ cla_w,
                                                  float* __restrict__ Vs) {
  const int tid = threadIdx.x, lane = tid & 63, wid = tid >> 6;
  const int row = blockIdx.x * 4 + wid;  // 0..8191 = t*512 + h
  const float4* src = (const float4*)(CM + (int64_t)row * 512);
  const float4* cw = (const float4*)cla_w;
  float4 a0 = src[lane * 2], a1 = src[lane * 2 + 1];
  float4 w0 = cw[lane * 2], w1 = cw[lane * 2 + 1];
  float s = a0.x * w0.x + a0.y * w0.y + a0.z * w0.z + a0.w * w0.w +
            a1.x * w1.x + a1.y * w1.y + a1.z * w1.z + a1.w * w1.w;
#pragma unroll
  for (int o = 32; o >= 1; o >>= 1) s += __shfl_xor(s, o);
  if (lane == 0) {
    int t = row >> 9, h = row & 511;
    Vs[h * 16 + t] = s;
  }
}

// -------- gmake3: Gt[c][k] = bf16( sum_h mlp_w[h][k] * U[h][c] ),
//          U = [attn | V];  block 80 computes cvec[c] = sum_h mlp_b[h]*U[h][c].
__global__ __launch_bounds__(256) void gmake3(
    const float* __restrict__ mlp_w, const float* __restrict__ mlp_b,
    const float* __restrict__ attn, const float* __restrict__ Vs,
    uint16_t* __restrict__ Gt, float* __restrict__ cvec) {
  const int tid = threadIdx.x;
  if (blockIdx.x == 80) {
    __shared__ float red[256];
    const int c = tid & 31, g = tid >> 5;
    float acc = 0.f;
    for (int h = g; h < 512; h += 8) {
      float uv = (c < 16) ? attn[h * 16 + c] : Vs[h * 16 + (c - 16)];
      acc += mlp_b[h] * uv;
    }
    red[tid] = acc;
    __syncthreads();
    if (tid < 32) {
      float s = 0.f;
#pragma unroll
      for (int g2 = 0; g2 < 8; ++g2) s += red[g2 * 32 + tid];
      cvec[tid] = s;
    }
    return;
  }

  __shared__ float Ls[4 * 64 * 33];  // [wave][k][c] padded: 33,792 B
  const int kl = tid & 63;
  const int wv = tid >> 6;
  const int k = blockIdx.x * 64 + kl;
  const bool valid = (k < 5000);
  const float* wp = mlp_w + (valid ? k : 0);
  const int h0 = wv * 128;

  float acc[32];
#pragma unroll
  for (int c = 0; c < 32; ++c) acc[c] = 0.f;

  for (int hh = 0; hh < 128; ++hh) {
    const int h = h0 + hh;
    float a = valid ? wp[(int64_t)h * 5000] : 0.f;
    const float4* ar = (const float4*)(attn + h * 16);
    const float4* vr = (const float4*)(Vs + h * 16);
#pragma unroll
    for (int q = 0; q < 4; ++q) {
      float4 u = ar[q];
      acc[q * 4 + 0] += a * u.x;
      acc[q * 4 + 1] += a * u.y;
      acc[q * 4 + 2] += a * u.z;
      acc[q * 4 + 3] += a * u.w;
    }
#pragma unroll
    for (int q = 0; q < 4; ++q) {
      float4 u = vr[q];
      acc[16 + q * 4 + 0] += a * u.x;
      acc[16 + q * 4 + 1] += a * u.y;
      acc[16 + q * 4 + 2] += a * u.z;
      acc[16 + q * 4 + 3] += a * u.w;
    }
  }
  float* lp = Ls + (wv * 64 + kl) * 33;  // bank (k+c)%32: conflict-free
#pragma unroll
  for (int c = 0; c < 32; ++c) lp[c] = acc[c];
  __syncthreads();
#pragma unroll
  for (int p = 0; p < 8; ++p) {
    int e = p * 256 + tid;
    int kk = e >> 5, c = e & 31;
    float s = Ls[kk * 33 + c] + Ls[(64 + kk) * 33 + c] +
              Ls[(128 + kk) * 33 + c] + Ls[(192 + kk) * 33 + c];
    Gt[(int64_t)c * 5120 + blockIdx.x * 64 + kk] = f2bf(s);
  }
}

// ------------- megagemm: P[z] = data[8192,5000] @ Gt[32,5120]^T -------------
// The only big-data kernel: A read exactly once. z=16 k-split (chunk 320):
// slab 32x320 bf16 = 20 KB -> 8 blocks/CU by LDS; __launch_bounds__(256,6)
// targets 24 waves/CU (VGPR cap ~85; round-7 build used 84 with 2x the
// unroll). More resident waves = more outstanding A-loads (this kernel is
// pure streaming). XOR swizzle unchanged: chunk c8 of row r stores source
// chunk c8^(r&7) (low-3-bit XOR keeps it in the same 8-group; slab row
// stride 640 B === 0 mod 32 banks, XOR spreads 8 rows over all banks).
__global__ __launch_bounds__(256, 6) void megagemm(
    const float* __restrict__ A,      // [8192][5000] fp32
    const uint16_t* __restrict__ Gt,  // [32][5120] bf16 (zero cols >= 5000)
    float* __restrict__ P) {          // [16][8192][32] fp32
  __shared__ __align__(16) uint16_t Gs[32 * 320];  // 20480 B
  const int tid = threadIdx.x;
  const int lane = tid & 63;
  const int w = tid >> 6;
  const int lin = blockIdx.x;
  const int mb = lin & 127;
  const int z = lin >> 7;  // 0..15
  const int m0 = mb * 64;
  const int k0 = z * 320;

  // stage slab: 1280 chunks of 16 B = 32 rows x 40 chunks, 5 rounds
#pragma unroll
  for (int p = 0; p < 5; ++p) {
    int e = p * 256 + tid;
    int row = e / 40;
    int c8 = e - row * 40;
    int src8 = c8 ^ (row & 7);  // low-3-bit XOR, stays in 8-group
    gld_lds16(Gt + (int64_t)row * 5120 + k0 + src8 * 8, &Gs[e * 8]);
  }
  __syncthreads();

  const int lr = lane & 15;
  const int kg = lane >> 4;
  const int key = lr & 7;
  const float* Arow = A + (int64_t)(m0 + w * 16 + lr) * 5000;

  f32x4 acc0 = {}, acc1 = {};
  if (z < 15) {  // clean path: all columns valid
#pragma unroll
    for (int step = 0; step < 10; ++step) {
      const int col = k0 + step * 32 + kg * 8;
      const float4* s = (const float4*)(Arow + col);
      float4 f0 = s[0], f1 = s[1];
      bf16x8 af = pack8(f0, f1);
      const int ch = (step * 4 + kg) ^ key;
      bf16x8 b0 = *(const bf16x8*)&Gs[lr * 320 + ch * 8];
      bf16x8 b1 = *(const bf16x8*)&Gs[(16 + lr) * 320 + ch * 8];
      acc0 = __builtin_amdgcn_mfma_f32_16x16x32_bf16(af, b0, acc0, 0, 0, 0);
      acc1 = __builtin_amdgcn_mfma_f32_16x16x32_bf16(af, b1, acc1, 0, 0, 0);
    }
  } else {  // z == 15: tail, clamp cols >= 5000 (x Gt zeros = 0)
#pragma unroll
    for (int step = 0; step < 10; ++step) {
      const int col = k0 + step * 32 + kg * 8;
      const float4* s = (const float4*)(Arow + (col < 5000 ? col : 0));
      float4 f0 = s[0], f1 = s[1];
      bf16x8 af = pack8(f0, f1);
      const int ch = (step * 4 + kg) ^ key;
      bf16x8 b0 = *(const bf16x8*)&Gs[lr * 320 + ch * 8];
      bf16x8 b1 = *(const bf16x8*)&Gs[(16 + lr) * 320 + ch * 8];
      acc0 = __builtin_amdgcn_mfma_f32_16x16x32_bf16(af, b0, acc0, 0, 0, 0);
      acc1 = __builtin_amdgcn_mfma_f32_16x16x32_bf16(af, b1, acc1, 0, 0, 0);
    }
  }

  // C/D layout: col = lane&15, row = (lane>>4)*4 + reg
  float* Pz = P + ((int64_t)z * 8192 + m0 + w * 16) * 32;
#pragma unroll
  for (int r = 0; r < 4; ++r) {
    int row = kg * 4 + r;
    Pz[row * 32 + lr] = acc0[r];
    Pz[row * 32 + 16 + lr] = acc1[r];
  }
}

// ------- epilogue: s,y = sum_z P + cvec; softmax(s); sigmoid(w.y+b) -------
// 8 rows/block; 32 lanes per row: c<16 carry s_c, c>=16 carry y_{c-16}.
__global__ __launch_bounds__(256) void epilogue(
    const float* __restrict__ P, const float* __restrict__ cvec,
    const float* __restrict__ cla_b, float* __restrict__ out) {
  const int tid = threadIdx.x;
  const int row = blockIdx.x * 8 + (tid >> 5);
  const int c = tid & 31;
  float s = cvec[c];
#pragma unroll
  for (int z = 0; z < 16; ++z)
    s += P[((int64_t)z * 8192 + row) * 32 + c];
  float yv = __shfl_xor(s, 16);  // partner: for c<16 this is y_c
  float m = s;
#pragma unroll
  for (int o = 8; o >= 1; o >>= 1) m = fmaxf(m, __shfl_xor(m, o));
  float e = __expf(s - m);
  float sum = e;
#pragma unroll
  for (int o = 8; o >= 1; o >>= 1) sum += __shfl_xor(sum, o);
  float val = (e / sum) * yv;
#pragma unroll
  for (int o = 8; o >= 1; o >>= 1) val += __shfl_xor(val, o);
  if (c == 0) out[row] = 1.f / (1.f + __expf(-(val + cla_b[0])));
}

// ---------------- launch ----------------
extern "C" void kernel_launch(void* const* d_in, const int* in_sizes, int n_in,
                              void* d_out, int out_size, void* d_ws,
                              size_t ws_size, hipStream_t stream) {
  const float* data = (const float*)d_in[0];   // [8192][5000]
  const float* mlp_w = (const float*)d_in[1];  // [512][5000]
  const float* mlp_b = (const float*)d_in[2];  // [512]
  const float* CM = (const float*)d_in[3];     // [16][512][512]
  const float* attn = (const float*)d_in[4];   // [512][16]
  const float* cla_w = (const float*)d_in[5];  // [512]
  const float* cla_b = (const float*)d_in[6];  // [1]
  float* out = (float*)d_out;                  // [8192]

  char* ws = (char*)d_ws;
  uint16_t* Gt = (uint16_t*)(ws + 0);   //  32*5120*2   =    327,680
  float* Vs = (float*)(ws + 327680);    //  512*16*4    =     32,768
  float* cvec = (float*)(ws + 360448);  //  32*4 (pad)  =        128
  float* P = (float*)(ws + 360576);     // 16*8192*32*4 = 16,777,216
  // total: 17,137,792 bytes

  // 1) V = CM . cla_w
  cmv_kernel<<<2048, 256, 0, stream>>>(CM, cla_w, Vs);
  // 2) Gt = bf16(mlp_w^T . [attn|V]) + cvec (block 80), single kernel
  gmake3<<<81, 256, 0, stream>>>(mlp_w, mlp_b, attn, Vs, Gt, cvec);
  // 3) the one big pass: [s|y] partials = data @ Gt^T  (z=16 k-split)
  megagemm<<<2048, 256, 0, stream>>>(data, Gt, P);
  // 4) softmax + mixture-collapse + sigmoid
  epilogue<<<1024, 256, 0, stream>>>(P, cvec, cla_b, out);
}